// Round 3
// baseline (1587.097 us; speedup 1.0000x reference)
//
#include <hip/hip_runtime.h>
#include <stdint.h>
#include <stddef.h>

#define NTOK 8192
#define DDIM 1024
#define HDIM 2048
#define NEXP 8

typedef __attribute__((ext_vector_type(8))) short short8;
typedef __attribute__((ext_vector_type(8))) unsigned short ushort8;
typedef __attribute__((ext_vector_type(4))) float floatx4;

#define AS1 __attribute__((address_space(1)))
#define AS3 __attribute__((address_space(3)))

// ws layout (bytes)
constexpr size_t OFF_CNT  = 0;                                        // 8 ints
constexpr size_t OFF_LIST = 256;                                      // E*N ints
constexpr size_t OFF_WTS  = OFF_LIST + (size_t)NEXP * NTOK * 4;       // E*N floats
constexpr size_t OFF_XBF  = OFF_WTS + (size_t)NEXP * NTOK * 4;        // N*D bf16
constexpr size_t OFF_W1T  = OFF_XBF + (size_t)NTOK * DDIM * 2;        // E*H*D bf16 (K-contig)
constexpr size_t OFF_W2T  = OFF_W1T + (size_t)NEXP * DDIM * HDIM * 2; // E*D*H bf16 (K-contig)
constexpr size_t OFF_H    = OFF_W2T + (size_t)NEXP * DDIM * HDIM * 2; // (K*N)*H bf16

__device__ __forceinline__ unsigned short f2bf(float f) {
  union { float f; unsigned u; } v; v.f = f;
  unsigned r = v.u + 0x7FFFu + ((v.u >> 16) & 1u);   // RNE, finite inputs
  return (unsigned short)(r >> 16);
}

// ---------------- gating (one wave per token) + fused x->bf16 pack ----------------
__global__ __launch_bounds__(256) void gate_kernel(
    const float* __restrict__ x, const float* __restrict__ Wg,
    const float* __restrict__ bg, const float* __restrict__ noise,
    int* __restrict__ counts, int* __restrict__ lists, float* __restrict__ wts,
    unsigned short* __restrict__ xbf) {
  int lane = threadIdx.x & 63;
  int wid  = threadIdx.x >> 6;
  int token = blockIdx.x * 4 + wid;
  const float* xr = x + (size_t)token * DDIM;
  unsigned short* xo = xbf + (size_t)token * DDIM;
  double acc[NEXP];
#pragma unroll
  for (int e = 0; e < NEXP; ++e) acc[e] = 0.0;
  for (int d = lane; d < DDIM; d += 64) {
    float xv = xr[d];
    xo[d] = f2bf(xv);
    const floatx4* wp = (const floatx4*)(Wg + d * NEXP);
    floatx4 w0 = wp[0], w1 = wp[1];
#pragma unroll
    for (int j = 0; j < 4; ++j) {
      acc[j]     += (double)xv * (double)w0[j];
      acc[4 + j] += (double)xv * (double)w1[j];
    }
  }
#pragma unroll
  for (int e = 0; e < NEXP; ++e)
#pragma unroll
    for (int off = 32; off > 0; off >>= 1) acc[e] += __shfl_xor(acc[e], off);
  if (lane == 0) {
    float nv[NEXP];
#pragma unroll
    for (int e = 0; e < NEXP; ++e) {
      float lg = (float)(acc[e] + (double)bg[e]);
      nv[e] = lg + 0.1f * noise[token * NEXP + e];
    }
    int i1 = 0; float v1 = nv[0];
#pragma unroll
    for (int e = 1; e < NEXP; ++e) if (nv[e] > v1) { v1 = nv[e]; i1 = e; }
    int i2 = -1; float v2 = -3.4e38f;
#pragma unroll
    for (int e = 0; e < NEXP; ++e) if (e != i1 && nv[e] > v2) { v2 = nv[e]; i2 = e; }
    float tt  = expf(v2 - v1);
    float w1s = 1.0f / (1.0f + tt);
    float w2s = tt / (1.0f + tt);
    int s1 = atomicAdd(&counts[i1], 1);
    lists[i1 * NTOK + s1] = token; wts[i1 * NTOK + s1] = w1s;
    int s2 = atomicAdd(&counts[i2], 1);
    lists[i2 * NTOK + s2] = token; wts[i2 * NTOK + s2] = w2s;
  }
}

// ---------------- W [e][R][C] f32 -> WT [e][C][R] bf16 ----------------
__global__ __launch_bounds__(256) void transpose_cvt_kernel(
    const float* __restrict__ W, unsigned short* __restrict__ WT, int R, int C) {
  __shared__ float tile[64][65];
  int e = blockIdx.z;
  const float* Win = W + (size_t)e * R * C;
  unsigned short* Wout = WT + (size_t)e * R * C;
  int c0 = blockIdx.x * 64, r0 = blockIdx.y * 64;
  int tx = threadIdx.x & 63, ty = threadIdx.x >> 6;
#pragma unroll
  for (int i = ty; i < 64; i += 4)
    tile[i][tx] = Win[(size_t)(r0 + i) * C + c0 + tx];
  __syncthreads();
  int cc = threadIdx.x >> 2, seg = (threadIdx.x & 3) * 16;
  ushort8 o0, o1;
#pragma unroll
  for (int j = 0; j < 8; ++j) o0[j] = f2bf(tile[seg + j][cc]);
#pragma unroll
  for (int j = 0; j < 8; ++j) o1[j] = f2bf(tile[seg + 8 + j][cc]);
  unsigned short* outp = Wout + (size_t)(c0 + cc) * R + r0 + seg;
  *(ushort8*)(outp) = o0;
  *(ushort8*)(outp + 8) = o1;
}

// ---------------- grouped GEMM: 128x256 tile, BK=32, 8 waves, 48KB LDS, 3 blocks/CU --------
// LDS: A[buf][128 rows][32 k] @ buf*8192 ; B[buf][256 rows][32 k] @ 16384 + buf*16384
// swizzle within a 64B row (4x16B chunks): slot = chunk ^ ((row>>1)&3)
// (linear gl_lds dest + inverse-swizzled global source + swizzled ds_read: rule #21)
template <int KDIM, int NDIM, bool IS_G1>
__global__ __launch_bounds__(512, 6) void moe_gemm_kernel(
    const unsigned short* __restrict__ Abase,
    const unsigned short* __restrict__ Bbase,
    const float* __restrict__ bias,
    const int* __restrict__ counts, const int* __restrict__ lists,
    const float* __restrict__ wts,
    unsigned short* __restrict__ Hout, float* __restrict__ Out) {
  __shared__ __align__(16) char smem[49152];
  constexpr int NT  = KDIM / 32;
  constexpr int NBY = NDIM / 256;

  // XCD-chunked bijective swizzle; bx-major inside (e,by) so B-panel stays L2-resident
  constexpr int TOTAL = 64 * NBY * NEXP;
  constexpr int Q8 = TOTAL / 8;
  int orig = (blockIdx.x & 7) * Q8 + (blockIdx.x >> 3);
  int bx   = orig & 63;
  int rest = orig >> 6;
  int by   = rest % NBY;
  int e    = rest / NBY;

  int Me, off_e = 0;
  {
    int c[8];
#pragma unroll
    for (int i = 0; i < 8; ++i) c[i] = counts[i];
    Me = c[e];
#pragma unroll
    for (int i = 0; i < 8; ++i) if (i < e) off_e += c[i];
  }
  if (bx * 128 >= Me) return;

  int tid = threadIdx.x;
  int lane = tid & 63, wid = tid >> 6;
  int wr = wid >> 2, wc = wid & 3;      // 2 x 4 waves -> per-wave 64x64
  int r16 = lane & 15, g4 = lane >> 4;

  // ---- staging sources (3 x gl_lds per K-tile: A rows 0-127; B rows 0-127, 128-255)
  int srow = tid >> 2;                  // 0..127
  int sc   = tid & 3;                   // stored slot
  int swz  = (srow >> 1) & 3;
  const unsigned short* srcA;
  {
    int lr = bx * 128 + srow;
    if (IS_G1) {
      int tok = lists[e * NTOK + (lr < Me ? lr : 0)];
      srcA = Abase + (size_t)tok * KDIM + (sc ^ swz) * 8;
    } else {
      int grow = off_e + (lr < Me ? lr : 0);
      srcA = Abase + (size_t)grow * KDIM + (sc ^ swz) * 8;
    }
  }
  int colb0 = by * 256 + srow;
  int colb1 = colb0 + 128;              // (row+128)>>1 & 3 == swz (128%4==0)
  const unsigned short* srcB0 = Bbase + ((size_t)e * NDIM + colb0) * KDIM + (sc ^ swz) * 8;
  const unsigned short* srcB1 = Bbase + ((size_t)e * NDIM + colb1) * KDIM + (sc ^ swz) * 8;

  auto stage = [&](int t) {
    int buf = t & 1;
    size_t ko = (size_t)t * 32;
    char* da = smem + buf * 8192 + tid * 16;
    char* db = smem + 16384 + buf * 16384 + tid * 16;
    __builtin_amdgcn_global_load_lds((const AS1 void*)(srcA  + ko), (AS3 void*)da, 16, 0, 0);
    __builtin_amdgcn_global_load_lds((const AS1 void*)(srcB0 + ko), (AS3 void*)db, 16, 0, 0);
    __builtin_amdgcn_global_load_lds((const AS1 void*)(srcB1 + ko), (AS3 void*)(db + 8192), 16, 0, 0);
  };

  // ---- fragment read offsets (constant; swizzled)
  int aoff[4], boff[4];
#pragma unroll
  for (int m = 0; m < 4; ++m) {
    int rowa = wr * 64 + m * 16 + r16;
    aoff[m] = rowa * 64 + ((g4 ^ ((rowa >> 1) & 3)) * 16);
  }
#pragma unroll
  for (int n = 0; n < 4; ++n) {
    int rowb = wc * 64 + n * 16 + r16;
    boff[n] = 16384 + rowb * 64 + ((g4 ^ ((rowb >> 1) & 3)) * 16);
  }

  floatx4 acc[4][4];
#pragma unroll
  for (int m = 0; m < 4; ++m)
#pragma unroll
    for (int n = 0; n < 4; ++n) acc[m][n] = (floatx4){0.f, 0.f, 0.f, 0.f};

  // ---- prologue: two K-tiles in flight
  stage(0);
  stage(1);
  asm volatile("s_waitcnt vmcnt(3)" ::: "memory");   // buf0 landed; buf1 in flight
  __builtin_amdgcn_s_barrier();
  __builtin_amdgcn_sched_barrier(0);

  for (int t = 0; t < NT; ++t) {
    const char* pa = smem + (t & 1) * 8192;
    const char* pb = smem + (t & 1) * 16384;
    short8 a[4], b[4];
#pragma unroll
    for (int m = 0; m < 4; ++m) a[m] = *(const short8*)(pa + aoff[m]);
#pragma unroll
    for (int n = 0; n < 4; ++n) b[n] = *(const short8*)(pb + boff[n]);
    __builtin_amdgcn_s_setprio(1);
#pragma unroll
    for (int m = 0; m < 4; ++m)
#pragma unroll
      for (int n = 0; n < 4; ++n)
        acc[m][n] = __builtin_amdgcn_mfma_f32_16x16x32_bf16(a[m], b[n], acc[m][n], 0, 0, 0);
    __builtin_amdgcn_s_setprio(0);
    if (t + 1 < NT) {
      __builtin_amdgcn_s_barrier();                  // all waves done reading buf(t&1)
      if (t + 2 < NT) {
        stage(t + 2);                                // overwrite buf(t&1)
        asm volatile("s_waitcnt vmcnt(3)" ::: "memory");  // tile t+1 landed; t+2 in flight
      } else {
        asm volatile("s_waitcnt vmcnt(0)" ::: "memory");  // tail: drain last tile
      }
      __builtin_amdgcn_s_barrier();
      __builtin_amdgcn_sched_barrier(0);
    }
  }

  // ---- epilogue: C/D layout col=lane&15, row=(lane>>4)*4+reg
  if constexpr (IS_G1) {
#pragma unroll
    for (int m = 0; m < 4; ++m) {
#pragma unroll
      for (int i = 0; i < 4; ++i) {
        int lrow = bx * 128 + wr * 64 + m * 16 + g4 * 4 + i;
        if (lrow < Me) {
          size_t hbase = (size_t)(off_e + lrow) * NDIM + by * 256;
#pragma unroll
          for (int n = 0; n < 4; ++n) {
            int col = wc * 64 + n * 16 + r16;
            float v = acc[m][n][i] + bias[e * NDIM + by * 256 + col];
            Hout[hbase + col] = f2bf(fmaxf(v, 0.f));
          }
        }
      }
    }
  } else {
#pragma unroll
    for (int m = 0; m < 4; ++m) {
#pragma unroll
      for (int i = 0; i < 4; ++i) {
        int lrow = bx * 128 + wr * 64 + m * 16 + g4 * 4 + i;
        if (lrow < Me) {
          int tok = lists[e * NTOK + lrow];
          float w = wts[e * NTOK + lrow];
          float* orow = Out + (size_t)tok * NDIM + by * 256;
#pragma unroll
          for (int n = 0; n < 4; ++n) {
            int col = wc * 64 + n * 16 + r16;
            float v = acc[m][n][i] + bias[e * NDIM + by * 256 + col];
            atomicAdd(orow + col, w * v);   // exactly 2 adds/element, commutative
          }
        }
      }
    }
  }
}

extern "C" void kernel_launch(void* const* d_in, const int* in_sizes, int n_in,
                              void* d_out, int out_size, void* d_ws, size_t ws_size,
                              hipStream_t stream) {
  (void)in_sizes; (void)n_in; (void)ws_size;
  const float* x     = (const float*)d_in[0];
  const float* W1    = (const float*)d_in[1];
  const float* b1    = (const float*)d_in[2];
  const float* W2    = (const float*)d_in[3];
  const float* b2    = (const float*)d_in[4];
  const float* Wg    = (const float*)d_in[5];
  const float* bg    = (const float*)d_in[6];
  const float* noise = (const float*)d_in[7];
  float* out = (float*)d_out;

  char* ws = (char*)d_ws;
  int*            counts = (int*)(ws + OFF_CNT);
  int*            lists  = (int*)(ws + OFF_LIST);
  float*          wts    = (float*)(ws + OFF_WTS);
  unsigned short* xbf    = (unsigned short*)(ws + OFF_XBF);
  unsigned short* w1t    = (unsigned short*)(ws + OFF_W1T);
  unsigned short* w2t    = (unsigned short*)(ws + OFF_W2T);
  unsigned short* h      = (unsigned short*)(ws + OFF_H);

  hipMemsetAsync(d_out, 0, (size_t)out_size * sizeof(float), stream);
  hipMemsetAsync(counts, 0, 256, stream);

  gate_kernel<<<NTOK / 4, 256, 0, stream>>>(x, Wg, bg, noise, counts, lists, wts, xbf);
  transpose_cvt_kernel<<<dim3(HDIM / 64, DDIM / 64, NEXP), 256, 0, stream>>>(W1, w1t, DDIM, HDIM);
  transpose_cvt_kernel<<<dim3(DDIM / 64, HDIM / 64, NEXP), 256, 0, stream>>>(W2, w2t, HDIM, DDIM);

  moe_gemm_kernel<DDIM, HDIM, true>
      <<<64 * (HDIM / 256) * NEXP, 512, 0, stream>>>(xbf, w1t, b1, counts, lists, wts, h, nullptr);
  moe_gemm_kernel<HDIM, DDIM, false>
      <<<64 * (DDIM / 256) * NEXP, 512, 0, stream>>>(h, w2t, b2, counts, lists, wts, nullptr, out);
}

// Round 6
// 667.173 us; speedup vs baseline: 2.3788x; 2.3788x over previous
//
#include <hip/hip_runtime.h>
#include <stdint.h>
#include <stddef.h>

#define NTOK 8192
#define DDIM 1024
#define HDIM 2048
#define NEXP 8

typedef __attribute__((ext_vector_type(8))) short short8;
typedef __attribute__((ext_vector_type(8))) unsigned short ushort8;
typedef __attribute__((ext_vector_type(4))) float floatx4;

#define AS1 __attribute__((address_space(1)))
#define AS3 __attribute__((address_space(3)))

// ws layout (bytes)
constexpr size_t OFF_CNT  = 0;                                        // 8 ints
constexpr size_t OFF_LIST = 256;                                      // E*N ints
constexpr size_t OFF_WTS  = OFF_LIST + (size_t)NEXP * NTOK * 4;       // E*N floats
constexpr size_t OFF_XBF  = OFF_WTS + (size_t)NEXP * NTOK * 4;        // N*D bf16
constexpr size_t OFF_W1T  = OFF_XBF + (size_t)NTOK * DDIM * 2;        // E*H*D bf16 (K-contig)
constexpr size_t OFF_W2T  = OFF_W1T + (size_t)NEXP * DDIM * HDIM * 2; // E*D*H bf16 (K-contig)
constexpr size_t OFF_H    = OFF_W2T + (size_t)NEXP * DDIM * HDIM * 2; // (K*N)*H bf16

__device__ __forceinline__ unsigned short f2bf(float f) {
  union { float f; unsigned u; } v; v.f = f;
  unsigned r = v.u + 0x7FFFu + ((v.u >> 16) & 1u);   // RNE, finite inputs
  return (unsigned short)(r >> 16);
}

// ---------------- gating (one wave per token) + fused x->bf16 pack ----------------
__global__ __launch_bounds__(256) void gate_kernel(
    const float* __restrict__ x, const float* __restrict__ Wg,
    const float* __restrict__ bg, const float* __restrict__ noise,
    int* __restrict__ counts, int* __restrict__ lists, float* __restrict__ wts,
    unsigned short* __restrict__ xbf) {
  int lane = threadIdx.x & 63;
  int wid  = threadIdx.x >> 6;
  int token = blockIdx.x * 4 + wid;
  const float* xr = x + (size_t)token * DDIM;
  unsigned short* xo = xbf + (size_t)token * DDIM;
  double acc[NEXP];
#pragma unroll
  for (int e = 0; e < NEXP; ++e) acc[e] = 0.0;
  for (int d = lane; d < DDIM; d += 64) {
    float xv = xr[d];
    xo[d] = f2bf(xv);
    const floatx4* wp = (const floatx4*)(Wg + d * NEXP);
    floatx4 w0 = wp[0], w1 = wp[1];
#pragma unroll
    for (int j = 0; j < 4; ++j) {
      acc[j]     += (double)xv * (double)w0[j];
      acc[4 + j] += (double)xv * (double)w1[j];
    }
  }
#pragma unroll
  for (int e = 0; e < NEXP; ++e)
#pragma unroll
    for (int off = 32; off > 0; off >>= 1) acc[e] += __shfl_xor(acc[e], off);
  if (lane == 0) {
    float nv[NEXP];
#pragma unroll
    for (int e = 0; e < NEXP; ++e) {
      float lg = (float)(acc[e] + (double)bg[e]);
      nv[e] = lg + 0.1f * noise[token * NEXP + e];
    }
    int i1 = 0; float v1 = nv[0];
#pragma unroll
    for (int e = 1; e < NEXP; ++e) if (nv[e] > v1) { v1 = nv[e]; i1 = e; }
    int i2 = -1; float v2 = -3.4e38f;
#pragma unroll
    for (int e = 0; e < NEXP; ++e) if (e != i1 && nv[e] > v2) { v2 = nv[e]; i2 = e; }
    float tt  = expf(v2 - v1);
    float w1s = 1.0f / (1.0f + tt);
    float w2s = tt / (1.0f + tt);
    int s1 = atomicAdd(&counts[i1], 1);
    lists[i1 * NTOK + s1] = token; wts[i1 * NTOK + s1] = w1s;
    int s2 = atomicAdd(&counts[i2], 1);
    lists[i2 * NTOK + s2] = token; wts[i2 * NTOK + s2] = w2s;
  }
}

// ---------------- W [e][R][C] f32 -> WT [e][C][R] bf16 ----------------
__global__ __launch_bounds__(256) void transpose_cvt_kernel(
    const float* __restrict__ W, unsigned short* __restrict__ WT, int R, int C) {
  __shared__ float tile[64][65];
  int e = blockIdx.z;
  const float* Win = W + (size_t)e * R * C;
  unsigned short* Wout = WT + (size_t)e * R * C;
  int c0 = blockIdx.x * 64, r0 = blockIdx.y * 64;
  int tx = threadIdx.x & 63, ty = threadIdx.x >> 6;
#pragma unroll
  for (int i = ty; i < 64; i += 4)
    tile[i][tx] = Win[(size_t)(r0 + i) * C + c0 + tx];
  __syncthreads();
  int cc = threadIdx.x >> 2, seg = (threadIdx.x & 3) * 16;
  ushort8 o0, o1;
#pragma unroll
  for (int j = 0; j < 8; ++j) o0[j] = f2bf(tile[seg + j][cc]);
#pragma unroll
  for (int j = 0; j < 8; ++j) o1[j] = f2bf(tile[seg + 8 + j][cc]);
  unsigned short* outp = Wout + (size_t)(c0 + cc) * R + r0 + seg;
  *(ushort8*)(outp) = o0;
  *(ushort8*)(outp + 8) = o1;
}

// ---------------- grouped GEMM: 128x128 tile, BK=32, 4 waves, 2-buf, syncthreads schedule ----
// LDS 32KB: A[buf][128][32] @ buf*8192 ; B[buf][128][32] @ 16384 + buf*8192. LINEAR layout
// (no swizzle: T2 is null on 2-phase schedules, m252). Schedule = R1/R3-proven:
// stage(t+1) -> read/MFMA(t) -> __syncthreads() (full drain; concurrency across blocks).
template <int KDIM, int NDIM, bool IS_G1>
__global__ __launch_bounds__(256) void moe_gemm_kernel(
    const unsigned short* __restrict__ Abase,
    const unsigned short* __restrict__ Bbase,
    const float* __restrict__ bias,
    const int* __restrict__ counts, const int* __restrict__ lists,
    const float* __restrict__ wts,
    unsigned short* __restrict__ Hout, float* __restrict__ Out) {
  __shared__ __align__(16) char smem[32768];
  constexpr int NT = KDIM / 32;

  int e  = blockIdx.z;
  int by = blockIdx.y;
  int bx = blockIdx.x;

  int Me, off_e = 0;
  {
    int c[8];
#pragma unroll
    for (int i = 0; i < 8; ++i) c[i] = counts[i];
    Me = c[e];
#pragma unroll
    for (int i = 0; i < 8; ++i) if (i < e) off_e += c[i];
  }
  if (bx * 128 >= Me) return;

  int tid = threadIdx.x;
  int lane = tid & 63, wid = tid >> 6;
  int wr = wid >> 1, wc = wid & 1;       // 2x2 waves, 64x64 output each
  int r16 = lane & 15, g4 = lane >> 4;

  // ---- staging sources: thread t covers LDS byte t*16 of each 4KB half-region
  //      row = tid>>2 (0..63) [+64 for second instr], 16B-chunk = tid&3 (linear)
  int r0 = tid >> 2;
  int ch = (tid & 3) * 8;                // element offset of this thread's 16B chunk
  const unsigned short *sA0, *sA1, *sB0, *sB1;
  {
    int lr0 = bx * 128 + r0, lr1 = lr0 + 64;
    if (IS_G1) {
      int tk0 = lists[e * NTOK + (lr0 < Me ? lr0 : 0)];
      int tk1 = lists[e * NTOK + (lr1 < Me ? lr1 : 0)];
      sA0 = Abase + (size_t)tk0 * KDIM + ch;
      sA1 = Abase + (size_t)tk1 * KDIM + ch;
    } else {
      sA0 = Abase + (size_t)(off_e + (lr0 < Me ? lr0 : 0)) * KDIM + ch;
      sA1 = Abase + (size_t)(off_e + (lr1 < Me ? lr1 : 0)) * KDIM + ch;
    }
    sB0 = Bbase + ((size_t)e * NDIM + by * 128 + r0) * KDIM + ch;
    sB1 = sB0 + (size_t)64 * KDIM;
  }

  auto stage = [&](int t) {              // 4 x global_load_lds(16B) per K-tile
    int buf = t & 1;
    size_t ko = (size_t)t * 32;
    char* da = smem + buf * 8192 + tid * 16;
    char* db = smem + 16384 + buf * 8192 + tid * 16;
    __builtin_amdgcn_global_load_lds((const AS1 void*)(sA0 + ko), (AS3 void*)da, 16, 0, 0);
    __builtin_amdgcn_global_load_lds((const AS1 void*)(sA1 + ko), (AS3 void*)(da + 4096), 16, 0, 0);
    __builtin_amdgcn_global_load_lds((const AS1 void*)(sB0 + ko), (AS3 void*)db, 16, 0, 0);
    __builtin_amdgcn_global_load_lds((const AS1 void*)(sB1 + ko), (AS3 void*)(db + 4096), 16, 0, 0);
  };

  // ---- fragment read offsets (linear layout: row*64 bytes + g4*16)
  int aoff[4], boff[4];
#pragma unroll
  for (int m = 0; m < 4; ++m) aoff[m] = (wr * 64 + m * 16 + r16) * 64 + g4 * 16;
#pragma unroll
  for (int n = 0; n < 4; ++n) boff[n] = (wc * 64 + n * 16 + r16) * 64 + g4 * 16;

  floatx4 acc[4][4];
#pragma unroll
  for (int m = 0; m < 4; ++m)
#pragma unroll
    for (int n = 0; n < 4; ++n) acc[m][n] = (floatx4){0.f, 0.f, 0.f, 0.f};

  stage(0);
  __syncthreads();                        // full drain: tile 0 landed (all waves)

  for (int t = 0; t < NT; ++t) {
    if (t + 1 < NT) stage(t + 1);         // issue next tile; flies during compute
    const char* pa = smem + (t & 1) * 8192;
    const char* pb = smem + 16384 + (t & 1) * 8192;
    short8 a[4], b[4];
#pragma unroll
    for (int m = 0; m < 4; ++m) a[m] = *(const short8*)(pa + aoff[m]);
#pragma unroll
    for (int n = 0; n < 4; ++n) b[n] = *(const short8*)(pb + boff[n]);
    __builtin_amdgcn_s_setprio(1);
#pragma unroll
    for (int m = 0; m < 4; ++m)
#pragma unroll
      for (int n = 0; n < 4; ++n)
        acc[m][n] = __builtin_amdgcn_mfma_f32_16x16x32_bf16(a[m], b[n], acc[m][n], 0, 0, 0);
    __builtin_amdgcn_s_setprio(0);
    __syncthreads();                      // drain tile t+1 + read-safety for buf t&1
  }

  // ---- epilogue: C/D layout col=lane&15, row=(lane>>4)*4+reg  [m89-verified]
  if constexpr (IS_G1) {
#pragma unroll
    for (int m = 0; m < 4; ++m) {
#pragma unroll
      for (int i = 0; i < 4; ++i) {
        int lrow = bx * 128 + wr * 64 + m * 16 + g4 * 4 + i;
        if (lrow < Me) {
          size_t hbase = (size_t)(off_e + lrow) * NDIM + by * 128;
#pragma unroll
          for (int n = 0; n < 4; ++n) {
            int col = wc * 64 + n * 16 + r16;
            float v = acc[m][n][i] + bias[e * NDIM + by * 128 + col];
            Hout[hbase + col] = f2bf(fmaxf(v, 0.f));
          }
        }
      }
    }
  } else {
#pragma unroll
    for (int m = 0; m < 4; ++m) {
#pragma unroll
      for (int i = 0; i < 4; ++i) {
        int lrow = bx * 128 + wr * 64 + m * 16 + g4 * 4 + i;
        if (lrow < Me) {
          int tok = lists[e * NTOK + lrow];
          float w = wts[e * NTOK + lrow];
          float* orow = Out + (size_t)tok * NDIM + by * 128;
#pragma unroll
          for (int n = 0; n < 4; ++n) {
            int col = wc * 64 + n * 16 + r16;
            float v = acc[m][n][i] + bias[e * NDIM + by * 128 + col];
            atomicAdd(orow + col, w * v);  // exactly 2 adds/element, commutative
          }
        }
      }
    }
  }
}

extern "C" void kernel_launch(void* const* d_in, const int* in_sizes, int n_in,
                              void* d_out, int out_size, void* d_ws, size_t ws_size,
                              hipStream_t stream) {
  (void)in_sizes; (void)n_in; (void)ws_size;
  const float* x     = (const float*)d_in[0];
  const float* W1    = (const float*)d_in[1];
  const float* b1    = (const float*)d_in[2];
  const float* W2    = (const float*)d_in[3];
  const float* b2    = (const float*)d_in[4];
  const float* Wg    = (const float*)d_in[5];
  const float* bg    = (const float*)d_in[6];
  const float* noise = (const float*)d_in[7];
  float* out = (float*)d_out;

  char* ws = (char*)d_ws;
  int*            counts = (int*)(ws + OFF_CNT);
  int*            lists  = (int*)(ws + OFF_LIST);
  float*          wts    = (float*)(ws + OFF_WTS);
  unsigned short* xbf    = (unsigned short*)(ws + OFF_XBF);
  unsigned short* w1t    = (unsigned short*)(ws + OFF_W1T);
  unsigned short* w2t    = (unsigned short*)(ws + OFF_W2T);
  unsigned short* h      = (unsigned short*)(ws + OFF_H);

  hipMemsetAsync(d_out, 0, (size_t)out_size * sizeof(float), stream);
  hipMemsetAsync(counts, 0, 256, stream);

  gate_kernel<<<NTOK / 4, 256, 0, stream>>>(x, Wg, bg, noise, counts, lists, wts, xbf);
  transpose_cvt_kernel<<<dim3(HDIM / 64, DDIM / 64, NEXP), 256, 0, stream>>>(W1, w1t, DDIM, HDIM);
  transpose_cvt_kernel<<<dim3(DDIM / 64, HDIM / 64, NEXP), 256, 0, stream>>>(W2, w2t, HDIM, DDIM);

  moe_gemm_kernel<DDIM, HDIM, true>
      <<<dim3(64, HDIM / 128, NEXP), 256, 0, stream>>>(xbf, w1t, b1, counts, lists, wts, h, nullptr);
  moe_gemm_kernel<HDIM, DDIM, false>
      <<<dim3(64, DDIM / 128, NEXP), 256, 0, stream>>>(h, w2t, b2, counts, lists, wts, nullptr, out);
}

// Round 7
// 537.376 us; speedup vs baseline: 2.9534x; 1.2415x over previous
//
#include <hip/hip_runtime.h>
#include <stdint.h>
#include <stddef.h>

#define NTOK 8192
#define DDIM 1024
#define HDIM 2048
#define NEXP 8

typedef __attribute__((ext_vector_type(8))) short short8;
typedef __attribute__((ext_vector_type(8))) unsigned short ushort8;
typedef __attribute__((ext_vector_type(4))) float floatx4;

#define AS1 __attribute__((address_space(1)))
#define AS3 __attribute__((address_space(3)))

// max row-tiles summed over experts: floor(16384/128)+8 = 136
#define MAXRT 136
#define MAXT1 (MAXRT * (HDIM / 128))   // 2176
#define MAXT2 (MAXRT * (DDIM / 128))   // 1088

// ws layout (bytes)
constexpr size_t OFF_CNT  = 0;                                        // 8 ints (+ pad)
constexpr size_t OFF_TB1  = 256;                                      // 1+MAXT1 ints
constexpr size_t OFF_TB2  = OFF_TB1 + 8960;                           // 1+MAXT2 ints
constexpr size_t OFF_LIST = OFF_TB2 + 4608;                           // E*N ints
constexpr size_t OFF_WTS  = OFF_LIST + (size_t)NEXP * NTOK * 4;       // E*N floats
constexpr size_t OFF_XBF  = OFF_WTS + (size_t)NEXP * NTOK * 4;        // N*D bf16
constexpr size_t OFF_W1T  = OFF_XBF + (size_t)NTOK * DDIM * 2;        // E*H*D bf16 (K-contig)
constexpr size_t OFF_W2T  = OFF_W1T + (size_t)NEXP * DDIM * HDIM * 2; // E*D*H bf16 (K-contig)
constexpr size_t OFF_H    = OFF_W2T + (size_t)NEXP * DDIM * HDIM * 2; // (K*N)*H bf16

__device__ __forceinline__ unsigned short f2bf(float f) {
  union { float f; unsigned u; } v; v.f = f;
  unsigned r = v.u + 0x7FFFu + ((v.u >> 16) & 1u);   // RNE, finite inputs
  return (unsigned short)(r >> 16);
}

// ---------------- gating (one wave per token) + fused x->bf16 pack ----------------
__global__ __launch_bounds__(256) void gate_kernel(
    const float* __restrict__ x, const float* __restrict__ Wg,
    const float* __restrict__ bg, const float* __restrict__ noise,
    int* __restrict__ counts, int* __restrict__ lists, float* __restrict__ wts,
    unsigned short* __restrict__ xbf) {
  int lane = threadIdx.x & 63;
  int wid  = threadIdx.x >> 6;
  int token = blockIdx.x * 4 + wid;
  const float* xr = x + (size_t)token * DDIM;
  unsigned short* xo = xbf + (size_t)token * DDIM;
  double acc[NEXP];
#pragma unroll
  for (int e = 0; e < NEXP; ++e) acc[e] = 0.0;
  for (int d = lane; d < DDIM; d += 64) {
    float xv = xr[d];
    xo[d] = f2bf(xv);
    const floatx4* wp = (const floatx4*)(Wg + d * NEXP);
    floatx4 w0 = wp[0], w1 = wp[1];
#pragma unroll
    for (int j = 0; j < 4; ++j) {
      acc[j]     += (double)xv * (double)w0[j];
      acc[4 + j] += (double)xv * (double)w1[j];
    }
  }
#pragma unroll
  for (int e = 0; e < NEXP; ++e)
#pragma unroll
    for (int off = 32; off > 0; off >>= 1) acc[e] += __shfl_xor(acc[e], off);
  if (lane == 0) {
    float nv[NEXP];
#pragma unroll
    for (int e = 0; e < NEXP; ++e) {
      float lg = (float)(acc[e] + (double)bg[e]);
      nv[e] = lg + 0.1f * noise[token * NEXP + e];
    }
    int i1 = 0; float v1 = nv[0];
#pragma unroll
    for (int e = 1; e < NEXP; ++e) if (nv[e] > v1) { v1 = nv[e]; i1 = e; }
    int i2 = -1; float v2 = -3.4e38f;
#pragma unroll
    for (int e = 0; e < NEXP; ++e) if (e != i1 && nv[e] > v2) { v2 = nv[e]; i2 = e; }
    float tt  = expf(v2 - v1);
    float w1s = 1.0f / (1.0f + tt);
    float w2s = tt / (1.0f + tt);
    int s1 = atomicAdd(&counts[i1], 1);
    lists[i1 * NTOK + s1] = token; wts[i1 * NTOK + s1] = w1s;
    int s2 = atomicAdd(&counts[i2], 1);
    lists[i2 * NTOK + s2] = token; wts[i2 * NTOK + s2] = w2s;
  }
}

// ---------------- tile-table build: exact work list, order (e, by, bx-fastest) ----------------
__global__ __launch_bounds__(256) void build_tiles_kernel(
    const int* __restrict__ counts, int* __restrict__ tb1, int* __restrict__ tb2) {
  int tid = threadIdx.x;
  int ct[8], cum[9];
  cum[0] = 0;
#pragma unroll
  for (int e = 0; e < 8; ++e) { ct[e] = (counts[e] + 127) >> 7; cum[e + 1] = cum[e] + ct[e]; }
  int nt = cum[8];
  constexpr int NBY1 = HDIM / 128, NBY2 = DDIM / 128;
  if (tid == 0) { tb1[0] = nt * NBY1; tb2[0] = nt * NBY2; }
  for (int idx = tid; idx < nt * NBY1; idx += 256) {
    int e = 0;
    while (idx >= cum[e + 1] * NBY1) ++e;
    int r = idx - cum[e] * NBY1;
    int by = r / ct[e], bx = r - by * ct[e];
    tb1[1 + idx] = (e << 16) | (bx << 8) | by;
  }
  for (int idx = tid; idx < nt * NBY2; idx += 256) {
    int e = 0;
    while (idx >= cum[e + 1] * NBY2) ++e;
    int r = idx - cum[e] * NBY2;
    int by = r / ct[e], bx = r - by * ct[e];
    tb2[1 + idx] = (e << 16) | (bx << 8) | by;
  }
}

// ---------------- W [e][R][C] f32 -> WT [e][C][R] bf16 ----------------
__global__ __launch_bounds__(256) void transpose_cvt_kernel(
    const float* __restrict__ W, unsigned short* __restrict__ WT, int R, int C) {
  __shared__ float tile[64][65];
  int e = blockIdx.z;
  const float* Win = W + (size_t)e * R * C;
  unsigned short* Wout = WT + (size_t)e * R * C;
  int c0 = blockIdx.x * 64, r0 = blockIdx.y * 64;
  int tx = threadIdx.x & 63, ty = threadIdx.x >> 6;
#pragma unroll
  for (int i = ty; i < 64; i += 4)
    tile[i][tx] = Win[(size_t)(r0 + i) * C + c0 + tx];
  __syncthreads();
  int cc = threadIdx.x >> 2, seg = (threadIdx.x & 3) * 16;
  ushort8 o0, o1;
#pragma unroll
  for (int j = 0; j < 8; ++j) o0[j] = f2bf(tile[seg + j][cc]);
#pragma unroll
  for (int j = 0; j < 8; ++j) o1[j] = f2bf(tile[seg + 8 + j][cc]);
  unsigned short* outp = Wout + (size_t)(c0 + cc) * R + r0 + seg;
  *(ushort8*)(outp) = o0;
  *(ushort8*)(outp + 8) = o1;
}

// ---------------- grouped GEMM: 128x128 tile, BK=32, 4 waves, 2-buf, counted-vmcnt 2-deep ----
// LDS 32KB: A[buf][128][32] @ buf*8192 ; B[buf][128][32] @ 16384 + buf*8192.
// Chunk swizzle within 64B row (R3-proven): stored slot s holds global chunk s^((row>>1)&3);
// applied as inverse-swizzled global SOURCE (linear gl_lds dest) + swizzled ds_read (rule #21).
// Counted-vmcnt (R3-proven): wait vmcnt(4) -> s_barrier -> compute -> s_barrier -> stage(t+2).
// NO other VMEM ops inside the K-loop (R4/R5 lesson: epilogue VMEM after stage corrupts count).
template <int KDIM, int NDIM, bool IS_G1>
__global__ __launch_bounds__(256) void moe_gemm_kernel(
    const unsigned short* __restrict__ Abase,
    const unsigned short* __restrict__ Bbase,
    const float* __restrict__ bias,
    const int* __restrict__ counts, const int* __restrict__ lists,
    const float* __restrict__ wts, const int* __restrict__ tbl,
    unsigned short* __restrict__ Hout, float* __restrict__ Out) {
  __shared__ __align__(16) char smem[32768];
  constexpr int NT = KDIM / 32;

  int ntiles = tbl[0];
  if ((int)blockIdx.x >= ntiles) return;
  int desc = tbl[1 + blockIdx.x];
  int e  = desc >> 16;
  int bx = (desc >> 8) & 0xff;
  int by = desc & 0xff;

  int Me, off_e = 0;
  {
    int c[8];
#pragma unroll
    for (int i = 0; i < 8; ++i) c[i] = counts[i];
    Me = c[e];
#pragma unroll
    for (int i = 0; i < 8; ++i) if (i < e) off_e += c[i];
  }

  int tid = threadIdx.x;
  int lane = tid & 63, wid = tid >> 6;
  int wr = wid >> 1, wc = wid & 1;       // 2x2 waves, 64x64 output each
  int r16 = lane & 15, g4 = lane >> 4;

  // ---- staging sources: thread t covers LDS byte t*16; row=tid>>2, stored slot=tid&3
  //      source chunk = slot ^ ((row>>1)&3)   (inverse swizzle)
  int r0 = tid >> 2;
  int ch = ((tid & 3) ^ ((r0 >> 1) & 3)) * 8;
  const unsigned short *sA0, *sA1, *sB0, *sB1;
  {
    int lr0 = bx * 128 + r0, lr1 = lr0 + 64;
    if (IS_G1) {
      int tk0 = lists[e * NTOK + (lr0 < Me ? lr0 : 0)];
      int tk1 = lists[e * NTOK + (lr1 < Me ? lr1 : 0)];
      sA0 = Abase + (size_t)tk0 * KDIM + ch;
      sA1 = Abase + (size_t)tk1 * KDIM + ch;
    } else {
      sA0 = Abase + (size_t)(off_e + (lr0 < Me ? lr0 : 0)) * KDIM + ch;
      sA1 = Abase + (size_t)(off_e + (lr1 < Me ? lr1 : 0)) * KDIM + ch;
    }
    sB0 = Bbase + ((size_t)e * NDIM + by * 128 + r0) * KDIM + ch;
    sB1 = sB0 + (size_t)64 * KDIM;
  }

  auto stage = [&](int t) {              // 4 x global_load_lds(16B) per K-tile
    int buf = t & 1;
    size_t ko = (size_t)t * 32;
    char* da = smem + buf * 8192 + tid * 16;
    char* db = smem + 16384 + buf * 8192 + tid * 16;
    __builtin_amdgcn_global_load_lds((const AS1 void*)(sA0 + ko), (AS3 void*)da, 16, 0, 0);
    __builtin_amdgcn_global_load_lds((const AS1 void*)(sA1 + ko), (AS3 void*)(da + 4096), 16, 0, 0);
    __builtin_amdgcn_global_load_lds((const AS1 void*)(sB0 + ko), (AS3 void*)db, 16, 0, 0);
    __builtin_amdgcn_global_load_lds((const AS1 void*)(sB1 + ko), (AS3 void*)(db + 4096), 16, 0, 0);
  };

  // ---- fragment read offsets (swizzled): row*64 + (g4 ^ ((row>>1)&3))*16 bytes
  int aoff[4], boff[4];
#pragma unroll
  for (int m = 0; m < 4; ++m) {
    int rowa = wr * 64 + m * 16 + r16;
    aoff[m] = rowa * 64 + ((g4 ^ ((rowa >> 1) & 3)) * 16);
  }
#pragma unroll
  for (int n = 0; n < 4; ++n) {
    int rowb = wc * 64 + n * 16 + r16;
    boff[n] = 16384 + rowb * 64 + ((g4 ^ ((rowb >> 1) & 3)) * 16);
  }

  floatx4 acc[4][4];
#pragma unroll
  for (int m = 0; m < 4; ++m)
#pragma unroll
    for (int n = 0; n < 4; ++n) acc[m][n] = (floatx4){0.f, 0.f, 0.f, 0.f};

  stage(0);
  stage(1);

  for (int t = 0; t < NT; ++t) {
    if (t + 1 < NT) { asm volatile("s_waitcnt vmcnt(4)" ::: "memory"); }
    else            { asm volatile("s_waitcnt vmcnt(0)" ::: "memory"); }
    __builtin_amdgcn_s_barrier();             // all waves' tile-t loads landed
    __builtin_amdgcn_sched_barrier(0);        // no ds_read hoists above barrier
    const char* pa = smem + (t & 1) * 8192;
    const char* pb = smem + (t & 1) * 8192;   // boff already includes +16384
    short8 a[4], b[4];
#pragma unroll
    for (int m = 0; m < 4; ++m) a[m] = *(const short8*)(pa + aoff[m]);
#pragma unroll
    for (int n = 0; n < 4; ++n) b[n] = *(const short8*)(pb + boff[n]);
    __builtin_amdgcn_s_setprio(1);
#pragma unroll
    for (int m = 0; m < 4; ++m)
#pragma unroll
      for (int n = 0; n < 4; ++n)
        acc[m][n] = __builtin_amdgcn_mfma_f32_16x16x32_bf16(a[m], b[n], acc[m][n], 0, 0, 0);
    __builtin_amdgcn_s_setprio(0);
    __builtin_amdgcn_s_barrier();             // all waves done reading buf t&1
    __builtin_amdgcn_sched_barrier(0);        // no gl_lds sinks above barrier
    if (t + 2 < NT) stage(t + 2);             // overwrite buf t&1; stays in flight
  }

  // ---- epilogue: C/D layout col=lane&15, row=(lane>>4)*4+reg  [m89-verified]
  if constexpr (IS_G1) {
#pragma unroll
    for (int m = 0; m < 4; ++m) {
#pragma unroll
      for (int i = 0; i < 4; ++i) {
        int lrow = bx * 128 + wr * 64 + m * 16 + g4 * 4 + i;
        if (lrow < Me) {
          size_t hbase = (size_t)(off_e + lrow) * NDIM + by * 128;
#pragma unroll
          for (int n = 0; n < 4; ++n) {
            int col = wc * 64 + n * 16 + r16;
            float v = acc[m][n][i] + bias[e * NDIM + by * 128 + col];
            Hout[hbase + col] = f2bf(fmaxf(v, 0.f));
          }
        }
      }
    }
  } else {
#pragma unroll
    for (int m = 0; m < 4; ++m) {
#pragma unroll
      for (int i = 0; i < 4; ++i) {
        int lrow = bx * 128 + wr * 64 + m * 16 + g4 * 4 + i;
        if (lrow < Me) {
          int tok = lists[e * NTOK + lrow];
          float w = wts[e * NTOK + lrow];
          float* orow = Out + (size_t)tok * NDIM + by * 128;
#pragma unroll
          for (int n = 0; n < 4; ++n) {
            int col = wc * 64 + n * 16 + r16;
            float v = acc[m][n][i] + bias[e * NDIM + by * 128 + col];
            atomicAdd(orow + col, w * v);  // exactly 2 adds/element, commutative
          }
        }
      }
    }
  }
}

extern "C" void kernel_launch(void* const* d_in, const int* in_sizes, int n_in,
                              void* d_out, int out_size, void* d_ws, size_t ws_size,
                              hipStream_t stream) {
  (void)in_sizes; (void)n_in; (void)ws_size;
  const float* x     = (const float*)d_in[0];
  const float* W1    = (const float*)d_in[1];
  const float* b1    = (const float*)d_in[2];
  const float* W2    = (const float*)d_in[3];
  const float* b2    = (const float*)d_in[4];
  const float* Wg    = (const float*)d_in[5];
  const float* bg    = (const float*)d_in[6];
  const float* noise = (const float*)d_in[7];
  float* out = (float*)d_out;

  char* ws = (char*)d_ws;
  int*            counts = (int*)(ws + OFF_CNT);
  int*            tb1    = (int*)(ws + OFF_TB1);
  int*            tb2    = (int*)(ws + OFF_TB2);
  int*            lists  = (int*)(ws + OFF_LIST);
  float*          wts    = (float*)(ws + OFF_WTS);
  unsigned short* xbf    = (unsigned short*)(ws + OFF_XBF);
  unsigned short* w1t    = (unsigned short*)(ws + OFF_W1T);
  unsigned short* w2t    = (unsigned short*)(ws + OFF_W2T);
  unsigned short* h      = (unsigned short*)(ws + OFF_H);

  hipMemsetAsync(d_out, 0, (size_t)out_size * sizeof(float), stream);
  hipMemsetAsync(counts, 0, 256, stream);

  gate_kernel<<<NTOK / 4, 256, 0, stream>>>(x, Wg, bg, noise, counts, lists, wts, xbf);
  build_tiles_kernel<<<1, 256, 0, stream>>>(counts, tb1, tb2);
  transpose_cvt_kernel<<<dim3(HDIM / 64, DDIM / 64, NEXP), 256, 0, stream>>>(W1, w1t, DDIM, HDIM);
  transpose_cvt_kernel<<<dim3(DDIM / 64, HDIM / 64, NEXP), 256, 0, stream>>>(W2, w2t, HDIM, DDIM);

  moe_gemm_kernel<DDIM, HDIM, true>
      <<<MAXT1, 256, 0, stream>>>(xbf, w1t, b1, counts, lists, wts, tb1, h, nullptr);
  moe_gemm_kernel<HDIM, DDIM, false>
      <<<MAXT2, 256, 0, stream>>>(h, w2t, b2, counts, lists, wts, tb2, nullptr, out);
}

// Round 8
// 383.100 us; speedup vs baseline: 4.1428x; 1.4027x over previous
//
#include <hip/hip_runtime.h>
#include <stdint.h>
#include <stddef.h>

#define NTOK 8192
#define DDIM 1024
#define HDIM 2048
#define NEXP 8

typedef __attribute__((ext_vector_type(8))) short short8;
typedef __attribute__((ext_vector_type(8))) unsigned short ushort8;
typedef __attribute__((ext_vector_type(4))) float floatx4;

#define AS1 __attribute__((address_space(1)))
#define AS3 __attribute__((address_space(3)))

// max row-tiles summed over experts: floor(16384/128)+8 = 136
#define MAXRT 136
#define MAXT1 (MAXRT * (HDIM / 128))   // 2176
#define MAXT2 (MAXRT * (DDIM / 128))   // 1088

// ws layout (bytes)
constexpr size_t OFF_CNT  = 0;                                        // 8 ints
constexpr size_t OFF_TB1  = 256;                                      // 1+MAXT1 ints
constexpr size_t OFF_TB2  = OFF_TB1 + 8960;                           // 1+MAXT2 ints
constexpr size_t OFF_TKI  = OFF_TB2 + 4608;                           // NTOK int2
constexpr size_t OFF_TKW  = OFF_TKI + (size_t)NTOK * 8;               // NTOK float2
constexpr size_t OFF_LIST = OFF_TKW + (size_t)NTOK * 8;               // E*N ints
constexpr size_t OFF_WTS  = OFF_LIST + (size_t)NEXP * NTOK * 4;       // E*N floats
constexpr size_t OFF_XBF  = OFF_WTS + (size_t)NEXP * NTOK * 4;        // N*D bf16
constexpr size_t OFF_W1T  = OFF_XBF + (size_t)NTOK * DDIM * 2;        // E*H*D bf16 (K-contig)
constexpr size_t OFF_W2T  = OFF_W1T + (size_t)NEXP * DDIM * HDIM * 2; // E*D*H bf16 (K-contig)
constexpr size_t OFF_H    = OFF_W2T + (size_t)NEXP * DDIM * HDIM * 2; // (K*N)*H bf16

__device__ __forceinline__ unsigned short f2bf(float f) {
  union { float f; unsigned u; } v; v.f = f;
  unsigned r = v.u + 0x7FFFu + ((v.u >> 16) & 1u);   // RNE, finite inputs
  return (unsigned short)(r >> 16);
}

// ---------------- gating (one wave per token) + fused x->bf16 pack; NO atomics ----------------
__global__ __launch_bounds__(256) void gate_kernel(
    const float* __restrict__ x, const float* __restrict__ Wg,
    const float* __restrict__ bg, const float* __restrict__ noise,
    int2* __restrict__ tki, float2* __restrict__ tkw,
    unsigned short* __restrict__ xbf) {
  int lane = threadIdx.x & 63;
  int wid  = threadIdx.x >> 6;
  int token = blockIdx.x * 4 + wid;
  const float* xr = x + (size_t)token * DDIM;
  unsigned short* xo = xbf + (size_t)token * DDIM;
  double acc[NEXP];
#pragma unroll
  for (int e = 0; e < NEXP; ++e) acc[e] = 0.0;
  for (int d = lane; d < DDIM; d += 64) {
    float xv = xr[d];
    xo[d] = f2bf(xv);
    const floatx4* wp = (const floatx4*)(Wg + d * NEXP);
    floatx4 w0 = wp[0], w1 = wp[1];
#pragma unroll
    for (int j = 0; j < 4; ++j) {
      acc[j]     += (double)xv * (double)w0[j];
      acc[4 + j] += (double)xv * (double)w1[j];
    }
  }
#pragma unroll
  for (int e = 0; e < NEXP; ++e)
#pragma unroll
    for (int off = 32; off > 0; off >>= 1) acc[e] += __shfl_xor(acc[e], off);
  if (lane == 0) {
    float nv[NEXP];
#pragma unroll
    for (int e = 0; e < NEXP; ++e) {
      float lg = (float)(acc[e] + (double)bg[e]);
      nv[e] = lg + 0.1f * noise[token * NEXP + e];
    }
    int i1 = 0; float v1 = nv[0];
#pragma unroll
    for (int e = 1; e < NEXP; ++e) if (nv[e] > v1) { v1 = nv[e]; i1 = e; }
    int i2 = -1; float v2 = -3.4e38f;
#pragma unroll
    for (int e = 0; e < NEXP; ++e) if (e != i1 && nv[e] > v2) { v2 = nv[e]; i2 = e; }
    float tt  = expf(v2 - v1);
    tki[token] = make_int2(i1, i2);
    tkw[token] = make_float2(1.0f / (1.0f + tt), tt / (1.0f + tt));
  }
}

// ---------------- scatter: one block per expert, ballot-compaction, deterministic ----------------
__global__ __launch_bounds__(256) void scatter_kernel(
    const int2* __restrict__ tki, const float2* __restrict__ tkw,
    int* __restrict__ counts, int* __restrict__ lists, float* __restrict__ wts) {
  int e = blockIdx.x;
  int tid = threadIdx.x;
  int lane = tid & 63, wid = tid >> 6;
  __shared__ int wave_cnt[4];
  __shared__ int run_total;
  if (tid == 0) run_total = 0;
  __syncthreads();
  for (int t0 = 0; t0 < NTOK; t0 += 256) {
    int tok = t0 + tid;
    int2 ki = tki[tok];
    float2 kw = tkw[tok];
    bool sel = (ki.x == e) || (ki.y == e);
    float w = (ki.x == e) ? kw.x : kw.y;
    unsigned long long mask = __ballot(sel);
    int pos = __popcll(mask & ((1ull << lane) - 1ull));
    if (lane == 0) wave_cnt[wid] = __popcll(mask);
    __syncthreads();
    int base = run_total;
    for (int i = 0; i < wid; ++i) base += wave_cnt[i];
    if (sel) {
      lists[e * NTOK + base + pos] = tok;
      wts[e * NTOK + base + pos] = w;
    }
    __syncthreads();
    if (tid == 0) run_total += wave_cnt[0] + wave_cnt[1] + wave_cnt[2] + wave_cnt[3];
    __syncthreads();
  }
  if (tid == 0) counts[e] = run_total;
}

// ---------------- tile-table build: exact work list, order (e, by, bx-fastest) ----------------
__global__ __launch_bounds__(256) void build_tiles_kernel(
    const int* __restrict__ counts, int* __restrict__ tb1, int* __restrict__ tb2) {
  int tid = threadIdx.x;
  int ct[8], cum[9];
  cum[0] = 0;
#pragma unroll
  for (int e = 0; e < 8; ++e) { ct[e] = (counts[e] + 127) >> 7; cum[e + 1] = cum[e] + ct[e]; }
  int nt = cum[8];
  constexpr int NBY1 = HDIM / 128, NBY2 = DDIM / 128;
  if (tid == 0) { tb1[0] = nt * NBY1; tb2[0] = nt * NBY2; }
  for (int idx = tid; idx < nt * NBY1; idx += 256) {
    int e = 0;
    while (idx >= cum[e + 1] * NBY1) ++e;
    int r = idx - cum[e] * NBY1;
    int by = r / ct[e], bx = r - by * ct[e];
    tb1[1 + idx] = (e << 16) | (bx << 8) | by;
  }
  for (int idx = tid; idx < nt * NBY2; idx += 256) {
    int e = 0;
    while (idx >= cum[e + 1] * NBY2) ++e;
    int r = idx - cum[e] * NBY2;
    int by = r / ct[e], bx = r - by * ct[e];
    tb2[1 + idx] = (e << 16) | (bx << 8) | by;
  }
}

// ---------------- W [e][R][C] f32 -> WT [e][C][R] bf16 ----------------
__global__ __launch_bounds__(256) void transpose_cvt_kernel(
    const float* __restrict__ W, unsigned short* __restrict__ WT, int R, int C) {
  __shared__ float tile[64][65];
  int e = blockIdx.z;
  const float* Win = W + (size_t)e * R * C;
  unsigned short* Wout = WT + (size_t)e * R * C;
  int c0 = blockIdx.x * 64, r0 = blockIdx.y * 64;
  int tx = threadIdx.x & 63, ty = threadIdx.x >> 6;
#pragma unroll
  for (int i = ty; i < 64; i += 4)
    tile[i][tx] = Win[(size_t)(r0 + i) * C + c0 + tx];
  __syncthreads();
  int cc = threadIdx.x >> 2, seg = (threadIdx.x & 3) * 16;
  ushort8 o0, o1;
#pragma unroll
  for (int j = 0; j < 8; ++j) o0[j] = f2bf(tile[seg + j][cc]);
#pragma unroll
  for (int j = 0; j < 8; ++j) o1[j] = f2bf(tile[seg + 8 + j][cc]);
  unsigned short* outp = Wout + (size_t)(c0 + cc) * R + r0 + seg;
  *(ushort8*)(outp) = o0;
  *(ushort8*)(outp + 8) = o1;
}

// ---------------- grouped GEMM: 128x128 tile, BK=32, 4 waves, 2-buf, counted-vmcnt 2-deep ----
// (unchanged from R7 — passed at absmax 0.0156)
template <int KDIM, int NDIM, bool IS_G1>
__global__ __launch_bounds__(256) void moe_gemm_kernel(
    const unsigned short* __restrict__ Abase,
    const unsigned short* __restrict__ Bbase,
    const float* __restrict__ bias,
    const int* __restrict__ counts, const int* __restrict__ lists,
    const float* __restrict__ wts, const int* __restrict__ tbl,
    unsigned short* __restrict__ Hout, float* __restrict__ Out) {
  __shared__ __align__(16) char smem[32768];
  constexpr int NT = KDIM / 32;

  int ntiles = tbl[0];
  if ((int)blockIdx.x >= ntiles) return;
  int desc = tbl[1 + blockIdx.x];
  int e  = desc >> 16;
  int bx = (desc >> 8) & 0xff;
  int by = desc & 0xff;

  int Me, off_e = 0;
  {
    int c[8];
#pragma unroll
    for (int i = 0; i < 8; ++i) c[i] = counts[i];
    Me = c[e];
#pragma unroll
    for (int i = 0; i < 8; ++i) if (i < e) off_e += c[i];
  }

  int tid = threadIdx.x;
  int lane = tid & 63, wid = tid >> 6;
  int wr = wid >> 1, wc = wid & 1;       // 2x2 waves, 64x64 output each
  int r16 = lane & 15, g4 = lane >> 4;

  int r0 = tid >> 2;
  int ch = ((tid & 3) ^ ((r0 >> 1) & 3)) * 8;
  const unsigned short *sA0, *sA1, *sB0, *sB1;
  {
    int lr0 = bx * 128 + r0, lr1 = lr0 + 64;
    if (IS_G1) {
      int tk0 = lists[e * NTOK + (lr0 < Me ? lr0 : 0)];
      int tk1 = lists[e * NTOK + (lr1 < Me ? lr1 : 0)];
      sA0 = Abase + (size_t)tk0 * KDIM + ch;
      sA1 = Abase + (size_t)tk1 * KDIM + ch;
    } else {
      sA0 = Abase + (size_t)(off_e + (lr0 < Me ? lr0 : 0)) * KDIM + ch;
      sA1 = Abase + (size_t)(off_e + (lr1 < Me ? lr1 : 0)) * KDIM + ch;
    }
    sB0 = Bbase + ((size_t)e * NDIM + by * 128 + r0) * KDIM + ch;
    sB1 = sB0 + (size_t)64 * KDIM;
  }

  auto stage = [&](int t) {
    int buf = t & 1;
    size_t ko = (size_t)t * 32;
    char* da = smem + buf * 8192 + tid * 16;
    char* db = smem + 16384 + buf * 8192 + tid * 16;
    __builtin_amdgcn_global_load_lds((const AS1 void*)(sA0 + ko), (AS3 void*)da, 16, 0, 0);
    __builtin_amdgcn_global_load_lds((const AS1 void*)(sA1 + ko), (AS3 void*)(da + 4096), 16, 0, 0);
    __builtin_amdgcn_global_load_lds((const AS1 void*)(sB0 + ko), (AS3 void*)db, 16, 0, 0);
    __builtin_amdgcn_global_load_lds((const AS1 void*)(sB1 + ko), (AS3 void*)(db + 4096), 16, 0, 0);
  };

  int aoff[4], boff[4];
#pragma unroll
  for (int m = 0; m < 4; ++m) {
    int rowa = wr * 64 + m * 16 + r16;
    aoff[m] = rowa * 64 + ((g4 ^ ((rowa >> 1) & 3)) * 16);
  }
#pragma unroll
  for (int n = 0; n < 4; ++n) {
    int rowb = wc * 64 + n * 16 + r16;
    boff[n] = 16384 + rowb * 64 + ((g4 ^ ((rowb >> 1) & 3)) * 16);
  }

  floatx4 acc[4][4];
#pragma unroll
  for (int m = 0; m < 4; ++m)
#pragma unroll
    for (int n = 0; n < 4; ++n) acc[m][n] = (floatx4){0.f, 0.f, 0.f, 0.f};

  stage(0);
  stage(1);

  for (int t = 0; t < NT; ++t) {
    if (t + 1 < NT) { asm volatile("s_waitcnt vmcnt(4)" ::: "memory"); }
    else            { asm volatile("s_waitcnt vmcnt(0)" ::: "memory"); }
    __builtin_amdgcn_s_barrier();
    __builtin_amdgcn_sched_barrier(0);
    const char* pa = smem + (t & 1) * 8192;
    const char* pb = smem + (t & 1) * 8192;   // boff already includes +16384
    short8 a[4], b[4];
#pragma unroll
    for (int m = 0; m < 4; ++m) a[m] = *(const short8*)(pa + aoff[m]);
#pragma unroll
    for (int n = 0; n < 4; ++n) b[n] = *(const short8*)(pb + boff[n]);
    __builtin_amdgcn_s_setprio(1);
#pragma unroll
    for (int m = 0; m < 4; ++m)
#pragma unroll
      for (int n = 0; n < 4; ++n)
        acc[m][n] = __builtin_amdgcn_mfma_f32_16x16x32_bf16(a[m], b[n], acc[m][n], 0, 0, 0);
    __builtin_amdgcn_s_setprio(0);
    __builtin_amdgcn_s_barrier();
    __builtin_amdgcn_sched_barrier(0);
    if (t + 2 < NT) stage(t + 2);
  }

  if constexpr (IS_G1) {
#pragma unroll
    for (int m = 0; m < 4; ++m) {
#pragma unroll
      for (int i = 0; i < 4; ++i) {
        int lrow = bx * 128 + wr * 64 + m * 16 + g4 * 4 + i;
        if (lrow < Me) {
          size_t hbase = (size_t)(off_e + lrow) * NDIM + by * 128;
#pragma unroll
          for (int n = 0; n < 4; ++n) {
            int col = wc * 64 + n * 16 + r16;
            float v = acc[m][n][i] + bias[e * NDIM + by * 128 + col];
            Hout[hbase + col] = f2bf(fmaxf(v, 0.f));
          }
        }
      }
    }
  } else {
#pragma unroll
    for (int m = 0; m < 4; ++m) {
#pragma unroll
      for (int i = 0; i < 4; ++i) {
        int lrow = bx * 128 + wr * 64 + m * 16 + g4 * 4 + i;
        if (lrow < Me) {
          int tok = lists[e * NTOK + lrow];
          float w = wts[e * NTOK + lrow];
          float* orow = Out + (size_t)tok * NDIM + by * 128;
#pragma unroll
          for (int n = 0; n < 4; ++n) {
            int col = wc * 64 + n * 16 + r16;
            float v = acc[m][n][i] + bias[e * NDIM + by * 128 + col];
            atomicAdd(orow + col, w * v);  // exactly 2 adds/element, commutative
          }
        }
      }
    }
  }
}

extern "C" void kernel_launch(void* const* d_in, const int* in_sizes, int n_in,
                              void* d_out, int out_size, void* d_ws, size_t ws_size,
                              hipStream_t stream) {
  (void)in_sizes; (void)n_in; (void)ws_size;
  const float* x     = (const float*)d_in[0];
  const float* W1    = (const float*)d_in[1];
  const float* b1    = (const float*)d_in[2];
  const float* W2    = (const float*)d_in[3];
  const float* b2    = (const float*)d_in[4];
  const float* Wg    = (const float*)d_in[5];
  const float* bg    = (const float*)d_in[6];
  const float* noise = (const float*)d_in[7];
  float* out = (float*)d_out;

  char* ws = (char*)d_ws;
  int*            counts = (int*)(ws + OFF_CNT);
  int*            tb1    = (int*)(ws + OFF_TB1);
  int*            tb2    = (int*)(ws + OFF_TB2);
  int2*           tki    = (int2*)(ws + OFF_TKI);
  float2*         tkw    = (float2*)(ws + OFF_TKW);
  int*            lists  = (int*)(ws + OFF_LIST);
  float*          wts    = (float*)(ws + OFF_WTS);
  unsigned short* xbf    = (unsigned short*)(ws + OFF_XBF);
  unsigned short* w1t    = (unsigned short*)(ws + OFF_W1T);
  unsigned short* w2t    = (unsigned short*)(ws + OFF_W2T);
  unsigned short* h      = (unsigned short*)(ws + OFF_H);

  hipMemsetAsync(d_out, 0, (size_t)out_size * sizeof(float), stream);
  hipMemsetAsync(counts, 0, 256, stream);

  gate_kernel<<<NTOK / 4, 256, 0, stream>>>(x, Wg, bg, noise, tki, tkw, xbf);
  scatter_kernel<<<NEXP, 256, 0, stream>>>(tki, tkw, counts, lists, wts);
  build_tiles_kernel<<<1, 256, 0, stream>>>(counts, tb1, tb2);
  transpose_cvt_kernel<<<dim3(HDIM / 64, DDIM / 64, NEXP), 256, 0, stream>>>(W1, w1t, DDIM, HDIM);
  transpose_cvt_kernel<<<dim3(DDIM / 64, HDIM / 64, NEXP), 256, 0, stream>>>(W2, w2t, HDIM, DDIM);

  moe_gemm_kernel<DDIM, HDIM, true>
      <<<MAXT1, 256, 0, stream>>>(xbf, w1t, b1, counts, lists, wts, tb1, h, nullptr);
  moe_gemm_kernel<HDIM, DDIM, false>
      <<<MAXT2, 256, 0, stream>>>(h, w2t, b2, counts, lists, wts, tb2, nullptr, out);
}

// Round 9
// 372.806 us; speedup vs baseline: 4.2572x; 1.0276x over previous
//
#include <hip/hip_runtime.h>
#include <stdint.h>
#include <stddef.h>

#define NTOK 8192
#define DDIM 1024
#define HDIM 2048
#define NEXP 8

typedef __attribute__((ext_vector_type(8))) short short8;
typedef __attribute__((ext_vector_type(8))) unsigned short ushort8;
typedef __attribute__((ext_vector_type(4))) float floatx4;

#define AS1 __attribute__((address_space(1)))
#define AS3 __attribute__((address_space(3)))

// max row-tiles summed over experts: floor(16384/128)+8 = 136
#define MAXRT 136
#define MAXT1 (MAXRT * (HDIM / 128))   // 2176
#define MAXT2 (MAXRT * (DDIM / 128))   // 1088

// ws layout (bytes)
constexpr size_t OFF_CNT  = 0;                                        // 8 ints
constexpr size_t OFF_TB1  = 256;                                      // 1+MAXT1 ints
constexpr size_t OFF_TB2  = OFF_TB1 + 8960;                           // 1+MAXT2 ints
constexpr size_t OFF_TKI  = OFF_TB2 + 4608;                           // NTOK int2
constexpr size_t OFF_TKW  = OFF_TKI + (size_t)NTOK * 8;               // NTOK float2
constexpr size_t OFF_LIST = OFF_TKW + (size_t)NTOK * 8;               // E*N ints
constexpr size_t OFF_WTS  = OFF_LIST + (size_t)NEXP * NTOK * 4;       // E*N floats
constexpr size_t OFF_XBF  = OFF_WTS + (size_t)NEXP * NTOK * 4;        // N*D bf16
constexpr size_t OFF_W1T  = OFF_XBF + (size_t)NTOK * DDIM * 2;        // E*H*D bf16 (K-contig)
constexpr size_t OFF_W2T  = OFF_W1T + (size_t)NEXP * DDIM * HDIM * 2; // E*D*H bf16 (K-contig)
constexpr size_t OFF_H    = OFF_W2T + (size_t)NEXP * DDIM * HDIM * 2; // (K*N)*H bf16

__device__ __forceinline__ unsigned short f2bf(float f) {
  union { float f; unsigned u; } v; v.f = f;
  unsigned r = v.u + 0x7FFFu + ((v.u >> 16) & 1u);   // RNE, finite inputs
  return (unsigned short)(r >> 16);
}

// ---------------- gating (one wave per token) + fused x->bf16 pack; NO atomics ----------------
__global__ __launch_bounds__(256) void gate_kernel(
    const float* __restrict__ x, const float* __restrict__ Wg,
    const float* __restrict__ bg, const float* __restrict__ noise,
    int2* __restrict__ tki, float2* __restrict__ tkw,
    unsigned short* __restrict__ xbf) {
  int lane = threadIdx.x & 63;
  int wid  = threadIdx.x >> 6;
  int token = blockIdx.x * 4 + wid;
  const float* xr = x + (size_t)token * DDIM;
  unsigned short* xo = xbf + (size_t)token * DDIM;
  double acc[NEXP];
#pragma unroll
  for (int e = 0; e < NEXP; ++e) acc[e] = 0.0;
  for (int d = lane; d < DDIM; d += 64) {
    float xv = xr[d];
    xo[d] = f2bf(xv);
    const floatx4* wp = (const floatx4*)(Wg + d * NEXP);
    floatx4 w0 = wp[0], w1 = wp[1];
#pragma unroll
    for (int j = 0; j < 4; ++j) {
      acc[j]     += (double)xv * (double)w0[j];
      acc[4 + j] += (double)xv * (double)w1[j];
    }
  }
#pragma unroll
  for (int e = 0; e < NEXP; ++e)
#pragma unroll
    for (int off = 32; off > 0; off >>= 1) acc[e] += __shfl_xor(acc[e], off);
  if (lane == 0) {
    float nv[NEXP];
#pragma unroll
    for (int e = 0; e < NEXP; ++e) {
      float lg = (float)(acc[e] + (double)bg[e]);
      nv[e] = lg + 0.1f * noise[token * NEXP + e];
    }
    int i1 = 0; float v1 = nv[0];
#pragma unroll
    for (int e = 1; e < NEXP; ++e) if (nv[e] > v1) { v1 = nv[e]; i1 = e; }
    int i2 = -1; float v2 = -3.4e38f;
#pragma unroll
    for (int e = 0; e < NEXP; ++e) if (e != i1 && nv[e] > v2) { v2 = nv[e]; i2 = e; }
    float tt  = expf(v2 - v1);
    tki[token] = make_int2(i1, i2);
    tkw[token] = make_float2(1.0f / (1.0f + tt), tt / (1.0f + tt));
  }
}

// ---------------- scatter: one block per expert, ballot-compaction, deterministic ----------------
__global__ __launch_bounds__(256) void scatter_kernel(
    const int2* __restrict__ tki, const float2* __restrict__ tkw,
    int* __restrict__ counts, int* __restrict__ lists, float* __restrict__ wts) {
  int e = blockIdx.x;
  int tid = threadIdx.x;
  int lane = tid & 63, wid = tid >> 6;
  __shared__ int wave_cnt[4];
  __shared__ int run_total;
  if (tid == 0) run_total = 0;
  __syncthreads();
  for (int t0 = 0; t0 < NTOK; t0 += 256) {
    int tok = t0 + tid;
    int2 ki = tki[tok];
    float2 kw = tkw[tok];
    bool sel = (ki.x == e) || (ki.y == e);
    float w = (ki.x == e) ? kw.x : kw.y;
    unsigned long long mask = __ballot(sel);
    int pos = __popcll(mask & ((1ull << lane) - 1ull));
    if (lane == 0) wave_cnt[wid] = __popcll(mask);
    __syncthreads();
    int base = run_total;
    for (int i = 0; i < wid; ++i) base += wave_cnt[i];
    if (sel) {
      lists[e * NTOK + base + pos] = tok;
      wts[e * NTOK + base + pos] = w;
    }
    __syncthreads();
    if (tid == 0) run_total += wave_cnt[0] + wave_cnt[1] + wave_cnt[2] + wave_cnt[3];
    __syncthreads();
  }
  if (tid == 0) counts[e] = run_total;
}

// ---------------- tile-table build: exact work list, order (e, by, bx-fastest) ----------------
__global__ __launch_bounds__(256) void build_tiles_kernel(
    const int* __restrict__ counts, int* __restrict__ tb1, int* __restrict__ tb2) {
  int tid = threadIdx.x;
  int ct[8], cum[9];
  cum[0] = 0;
#pragma unroll
  for (int e = 0; e < 8; ++e) { ct[e] = (counts[e] + 127) >> 7; cum[e + 1] = cum[e] + ct[e]; }
  int nt = cum[8];
  constexpr int NBY1 = HDIM / 128, NBY2 = DDIM / 128;
  if (tid == 0) { tb1[0] = nt * NBY1; tb2[0] = nt * NBY2; }
  for (int idx = tid; idx < nt * NBY1; idx += 256) {
    int e = 0;
    while (idx >= cum[e + 1] * NBY1) ++e;
    int r = idx - cum[e] * NBY1;
    int by = r / ct[e], bx = r - by * ct[e];
    tb1[1 + idx] = (e << 16) | (bx << 8) | by;
  }
  for (int idx = tid; idx < nt * NBY2; idx += 256) {
    int e = 0;
    while (idx >= cum[e + 1] * NBY2) ++e;
    int r = idx - cum[e] * NBY2;
    int by = r / ct[e], bx = r - by * ct[e];
    tb2[1 + idx] = (e << 16) | (bx << 8) | by;
  }
}

// ---------------- W [e][R][C] f32 -> WT [e][C][R] bf16 ----------------
__global__ __launch_bounds__(256) void transpose_cvt_kernel(
    const float* __restrict__ W, unsigned short* __restrict__ WT, int R, int C) {
  __shared__ float tile[64][65];
  int e = blockIdx.z;
  const float* Win = W + (size_t)e * R * C;
  unsigned short* Wout = WT + (size_t)e * R * C;
  int c0 = blockIdx.x * 64, r0 = blockIdx.y * 64;
  int tx = threadIdx.x & 63, ty = threadIdx.x >> 6;
#pragma unroll
  for (int i = ty; i < 64; i += 4)
    tile[i][tx] = Win[(size_t)(r0 + i) * C + c0 + tx];
  __syncthreads();
  int cc = threadIdx.x >> 2, seg = (threadIdx.x & 3) * 16;
  ushort8 o0, o1;
#pragma unroll
  for (int j = 0; j < 8; ++j) o0[j] = f2bf(tile[seg + j][cc]);
#pragma unroll
  for (int j = 0; j < 8; ++j) o1[j] = f2bf(tile[seg + 8 + j][cc]);
  unsigned short* outp = Wout + (size_t)(c0 + cc) * R + r0 + seg;
  *(ushort8*)(outp) = o0;
  *(ushort8*)(outp + 8) = o1;
}

// ---------------- grouped GEMM: 128x128 tile, BK=32, 4 waves, 3-buf, counted-vmcnt 3-deep ----
// LDS 48KB: A[3 bufs][128][32] @ buf*8192 ; B[3 bufs][128][32] @ 24576 + buf*8192.
// Chunk swizzle within 64B row: stored slot s holds chunk s^((row>>1)&3) (rule #21 pair).
// XCD-chunked bijective tile swizzle (m204): consecutive blocks round-robin XCDs, so give
// each XCD a CONTIGUOUS run of bx-fastest tiles -> B-panel lives in ONE L2, not 8.
// Only VMEM inside K-loop = stage gl_lds (counted-vmcnt invariant; R4/R5 lesson).
template <int KDIM, int NDIM, bool IS_G1>
__global__ __launch_bounds__(256) void moe_gemm_kernel(
    const unsigned short* __restrict__ Abase,
    const unsigned short* __restrict__ Bbase,
    const float* __restrict__ bias,
    const int* __restrict__ counts, const int* __restrict__ lists,
    const float* __restrict__ wts, const int* __restrict__ tbl,
    unsigned short* __restrict__ Hout, float* __restrict__ Out) {
  __shared__ __align__(16) char smem[49152];
  constexpr int NT = KDIM / 32;

  int ntiles = tbl[0];
  int bid = blockIdx.x;
  if (bid >= ntiles) return;
  // bijective XCD-chunk swizzle within [0, ntiles)
  int q = ntiles >> 3, rr = ntiles & 7;
  int xcd = bid & 7, within = bid >> 3;
  int widx = (xcd < rr ? xcd * (q + 1) : rr * (q + 1) + (xcd - rr) * q) + within;
  int desc = tbl[1 + widx];
  int e  = desc >> 16;
  int bx = (desc >> 8) & 0xff;
  int by = desc & 0xff;

  int Me, off_e = 0;
  {
    int c[8];
#pragma unroll
    for (int i = 0; i < 8; ++i) c[i] = counts[i];
    Me = c[e];
#pragma unroll
    for (int i = 0; i < 8; ++i) if (i < e) off_e += c[i];
  }

  int tid = threadIdx.x;
  int lane = tid & 63, wid = tid >> 6;
  int wr = wid >> 1, wc = wid & 1;       // 2x2 waves, 64x64 output each
  int r16 = lane & 15, g4 = lane >> 4;

  int r0 = tid >> 2;
  int ch = ((tid & 3) ^ ((r0 >> 1) & 3)) * 8;
  const unsigned short *sA0, *sA1, *sB0, *sB1;
  {
    int lr0 = bx * 128 + r0, lr1 = lr0 + 64;
    if (IS_G1) {
      int tk0 = lists[e * NTOK + (lr0 < Me ? lr0 : 0)];
      int tk1 = lists[e * NTOK + (lr1 < Me ? lr1 : 0)];
      sA0 = Abase + (size_t)tk0 * KDIM + ch;
      sA1 = Abase + (size_t)tk1 * KDIM + ch;
    } else {
      sA0 = Abase + (size_t)(off_e + (lr0 < Me ? lr0 : 0)) * KDIM + ch;
      sA1 = Abase + (size_t)(off_e + (lr1 < Me ? lr1 : 0)) * KDIM + ch;
    }
    sB0 = Bbase + ((size_t)e * NDIM + by * 128 + r0) * KDIM + ch;
    sB1 = sB0 + (size_t)64 * KDIM;
  }

  auto stage = [&](int t) {
    int buf = t % 3;
    size_t ko = (size_t)t * 32;
    char* da = smem + buf * 8192 + tid * 16;
    char* db = smem + 24576 + buf * 8192 + tid * 16;
    __builtin_amdgcn_global_load_lds((const AS1 void*)(sA0 + ko), (AS3 void*)da, 16, 0, 0);
    __builtin_amdgcn_global_load_lds((const AS1 void*)(sA1 + ko), (AS3 void*)(da + 4096), 16, 0, 0);
    __builtin_amdgcn_global_load_lds((const AS1 void*)(sB0 + ko), (AS3 void*)db, 16, 0, 0);
    __builtin_amdgcn_global_load_lds((const AS1 void*)(sB1 + ko), (AS3 void*)(db + 4096), 16, 0, 0);
  };

  int aoff[4], boff[4];
#pragma unroll
  for (int m = 0; m < 4; ++m) {
    int rowa = wr * 64 + m * 16 + r16;
    aoff[m] = rowa * 64 + ((g4 ^ ((rowa >> 1) & 3)) * 16);
  }
#pragma unroll
  for (int n = 0; n < 4; ++n) {
    int rowb = wc * 64 + n * 16 + r16;
    boff[n] = 24576 + rowb * 64 + ((g4 ^ ((rowb >> 1) & 3)) * 16);
  }

  floatx4 acc[4][4];
#pragma unroll
  for (int m = 0; m < 4; ++m)
#pragma unroll
    for (int n = 0; n < 4; ++n) acc[m][n] = (floatx4){0.f, 0.f, 0.f, 0.f};

  stage(0);
  stage(1);
  stage(2);

  for (int t = 0; t < NT; ++t) {
    if (t + 2 < NT)      { asm volatile("s_waitcnt vmcnt(8)" ::: "memory"); }
    else if (t + 1 < NT) { asm volatile("s_waitcnt vmcnt(4)" ::: "memory"); }
    else                 { asm volatile("s_waitcnt vmcnt(0)" ::: "memory"); }
    __builtin_amdgcn_s_barrier();
    __builtin_amdgcn_sched_barrier(0);
    const char* pa = smem + (t % 3) * 8192;
    const char* pb = smem + (t % 3) * 8192;   // boff already includes +24576
    short8 a[4], b[4];
#pragma unroll
    for (int m = 0; m < 4; ++m) a[m] = *(const short8*)(pa + aoff[m]);
#pragma unroll
    for (int n = 0; n < 4; ++n) b[n] = *(const short8*)(pb + boff[n]);
    __builtin_amdgcn_s_setprio(1);
#pragma unroll
    for (int m = 0; m < 4; ++m)
#pragma unroll
      for (int n = 0; n < 4; ++n)
        acc[m][n] = __builtin_amdgcn_mfma_f32_16x16x32_bf16(a[m], b[n], acc[m][n], 0, 0, 0);
    __builtin_amdgcn_s_setprio(0);
    __builtin_amdgcn_s_barrier();
    __builtin_amdgcn_sched_barrier(0);
    if (t + 3 < NT) stage(t + 3);
  }

  if constexpr (IS_G1) {
#pragma unroll
    for (int m = 0; m < 4; ++m) {
#pragma unroll
      for (int i = 0; i < 4; ++i) {
        int lrow = bx * 128 + wr * 64 + m * 16 + g4 * 4 + i;
        if (lrow < Me) {
          size_t hbase = (size_t)(off_e + lrow) * NDIM + by * 128;
#pragma unroll
          for (int n = 0; n < 4; ++n) {
            int col = wc * 64 + n * 16 + r16;
            float v = acc[m][n][i] + bias[e * NDIM + by * 128 + col];
            Hout[hbase + col] = f2bf(fmaxf(v, 0.f));
          }
        }
      }
    }
  } else {
#pragma unroll
    for (int m = 0; m < 4; ++m) {
#pragma unroll
      for (int i = 0; i < 4; ++i) {
        int lrow = bx * 128 + wr * 64 + m * 16 + g4 * 4 + i;
        if (lrow < Me) {
          int tok = lists[e * NTOK + lrow];
          float w = wts[e * NTOK + lrow];
          float* orow = Out + (size_t)tok * NDIM + by * 128;
#pragma unroll
          for (int n = 0; n < 4; ++n) {
            int col = wc * 64 + n * 16 + r16;
            float v = acc[m][n][i] + bias[e * NDIM + by * 128 + col];
            atomicAdd(orow + col, w * v);  // exactly 2 adds/element, commutative
          }
        }
      }
    }
  }
}

extern "C" void kernel_launch(void* const* d_in, const int* in_sizes, int n_in,
                              void* d_out, int out_size, void* d_ws, size_t ws_size,
                              hipStream_t stream) {
  (void)in_sizes; (void)n_in; (void)ws_size;
  const float* x     = (const float*)d_in[0];
  const float* W1    = (const float*)d_in[1];
  const float* b1    = (const float*)d_in[2];
  const float* W2    = (const float*)d_in[3];
  const float* b2    = (const float*)d_in[4];
  const float* Wg    = (const float*)d_in[5];
  const float* bg    = (const float*)d_in[6];
  const float* noise = (const float*)d_in[7];
  float* out = (float*)d_out;

  char* ws = (char*)d_ws;
  int*            counts = (int*)(ws + OFF_CNT);
  int*            tb1    = (int*)(ws + OFF_TB1);
  int*            tb2    = (int*)(ws + OFF_TB2);
  int2*           tki    = (int2*)(ws + OFF_TKI);
  float2*         tkw    = (float2*)(ws + OFF_TKW);
  int*            lists  = (int*)(ws + OFF_LIST);
  float*          wts    = (float*)(ws + OFF_WTS);
  unsigned short* xbf    = (unsigned short*)(ws + OFF_XBF);
  unsigned short* w1t    = (unsigned short*)(ws + OFF_W1T);
  unsigned short* w2t    = (unsigned short*)(ws + OFF_W2T);
  unsigned short* h      = (unsigned short*)(ws + OFF_H);

  hipMemsetAsync(d_out, 0, (size_t)out_size * sizeof(float), stream);
  hipMemsetAsync(counts, 0, 256, stream);

  gate_kernel<<<NTOK / 4, 256, 0, stream>>>(x, Wg, bg, noise, tki, tkw, xbf);
  scatter_kernel<<<NEXP, 256, 0, stream>>>(tki, tkw, counts, lists, wts);
  build_tiles_kernel<<<1, 256, 0, stream>>>(counts, tb1, tb2);
  transpose_cvt_kernel<<<dim3(HDIM / 64, DDIM / 64, NEXP), 256, 0, stream>>>(W1, w1t, DDIM, HDIM);
  transpose_cvt_kernel<<<dim3(DDIM / 64, HDIM / 64, NEXP), 256, 0, stream>>>(W2, w2t, HDIM, DDIM);

  moe_gemm_kernel<DDIM, HDIM, true>
      <<<MAXT1, 256, 0, stream>>>(xbf, w1t, b1, counts, lists, wts, tb1, h, nullptr);
  moe_gemm_kernel<HDIM, DDIM, false>
      <<<MAXT2, 256, 0, stream>>>(h, w2t, b2, counts, lists, wts, tb2, nullptr, out);
}